// Round 12
// baseline (132.480 us; speedup 1.0000x reference)
//
#include <hip/hip_runtime.h>

// B=2, H=16, S=2048, DK=DV=64; out flat = [B,H,S,DV] flat (raw reshape).
#define S_LEN 2048
#define DHEAD 64
#define BHEADS 32
#define NTILES 32                       // key tiles of 64
#define HEAD_ELEMS (S_LEN * DHEAD)
#define TENS_ELEMS (BHEADS * HEAD_ELEMS)
#define TILE_HALVES 4096                // 8 KB per (bh,tile) fragment block

typedef _Float16 half8_t __attribute__((ext_vector_type(8)));
typedef _Float16 half4_t __attribute__((ext_vector_type(4)));
typedef _Float16 half2_t __attribute__((ext_vector_type(2)));
typedef float float4_t __attribute__((ext_vector_type(4)));

// 1/sqrt(64) * log2(e), folded into K so scores land in exp2 domain
#define SC_LOG2E 0.18033688011112042f

// Fragment-linear layouts (16 B per lane per fragment):
//  Kf[bh][t][f=mt*2+kh][lane] : K[t*64 + mt*16 + (lane&15)][kh*32 + (lane>>4)*8 + j] * SC
//  Vf[bh][t][fv=vt*2+c][lane][j] : V[t*64 + c*32 + (j>>2)*16 + (lane>>4)*4 + (j&3)]
//                                   [vt*16 + (lane&15)]
// Key fact (R9): Vf's k-ordering equals the k-ordering of a P^T B-operand
// built by concatenating QK sub-tile outputs 2c (regs 0-3) and 2c+1 (regs
// 4-7), so PV can use mfma_f32_16x16x32_f16 directly — half the PV MFMAs.

// ---------------- prepass: build fragment-ordered K/VT ----------------
__global__ __launch_bounds__(256) void prep_kernel(const float* __restrict__ K,
                                                   const float* __restrict__ V,
                                                   _Float16* __restrict__ Kf,
                                                   _Float16* __restrict__ Vf) {
    __shared__ _Float16 tile[64][72];   // V tile [s][v], padded
    const int bh = blockIdx.x >> 5;
    const int t = blockIdx.x & 31;
    const int tid = threadIdx.x;

    const float* Ksrc = K + (bh * S_LEN + t * 64) * DHEAD;
    const float4* vs = (const float4*)(V + (bh * S_LEN + t * 64) * DHEAD);
#pragma unroll
    for (int it = 0; it < 4; ++it) {
        int i = it * 256 + tid;                 // 1024 float4 = 64x64 floats
        float4 vv = vs[i];
        int r = i >> 4, c4 = (i & 15) * 4;
        half4_t hv = {(_Float16)vv.x, (_Float16)vv.y, (_Float16)vv.z, (_Float16)vv.w};
        *(half4_t*)&tile[r][c4] = hv;
    }

    // K fragments: pure permutation of the fp32 tile, no LDS needed
    _Float16* kd = Kf + (bh * NTILES + t) * TILE_HALVES;
#pragma unroll
    for (int it = 0; it < 2; ++it) {
        int c = it * 256 + tid;                 // 512 chunks of 16 B
        int f = c >> 6, lane = c & 63;
        int row = (f >> 1) * 16 + (lane & 15);
        int d0 = (f & 1) * 32 + (lane >> 4) * 8;
        const float4* s = (const float4*)(Ksrc + row * DHEAD + d0);
        float4 a = s[0], b = s[1];
        half8_t h = {(_Float16)(a.x * SC_LOG2E), (_Float16)(a.y * SC_LOG2E),
                     (_Float16)(a.z * SC_LOG2E), (_Float16)(a.w * SC_LOG2E),
                     (_Float16)(b.x * SC_LOG2E), (_Float16)(b.y * SC_LOG2E),
                     (_Float16)(b.z * SC_LOG2E), (_Float16)(b.w * SC_LOG2E)};
        *(half8_t*)(kd + c * 8) = h;
    }
    __syncthreads();

    // VT fragments: transpose gather from LDS
    _Float16* vd = Vf + (bh * NTILES + t) * TILE_HALVES;
#pragma unroll
    for (int it = 0; it < 2; ++it) {
        int c = it * 256 + tid;
        int fv = c >> 6, lane = c & 63;
        int vt = fv >> 1, ktp = fv & 1;
        int v = vt * 16 + (lane & 15);
        int g = lane >> 4;
        half8_t h;
#pragma unroll
        for (int j = 0; j < 8; ++j) {
            int key = ktp * 32 + (j >> 2) * 16 + g * 4 + (j & 3);
            h[j] = tile[key][v];
        }
        *(half8_t*)(vd + c * 8) = h;
    }
}

// ---- attention: producer/consumer wave specialization (R20) ----
// Block = 4 waves = 2 k-splits x {1 producer, 1 consumer}. 128 q per block.
// Ledger: R11/R13/R14/R16/R17/R19 all null; R15 -9%; R18 (delete VALU work)
// WIN 45.0->43.3, quantitatively = deleted issue cycles. Diagnosis: wall =
// serialized pipe time. VALUBusy ~30% is exp2 (64/tile/wave x ~16cyc trans);
// MFMA ~34%; they never overlap because identical wave streams phase-lock
// (setprio can't fix: R15). Fix: structurally DIFFERENT streams.
//  producer(ks): QK MFMA + exp2 + pack -> pb to LDS  (trans-bound ~1.2k/chunk)
//  consumer(ks): PV MFMA from pb + V + lsum          (MFMA-bound ~0.4k/chunk)
// Chunk-granularity double-buffered pb handoff: pb[ks][buf][nq8][lane][8h]
// = 32 KB; producer's pb fragment IS the consumer's B-operand at the same
// lane -> write/read same address, no layout rederivation. Q staged in LDS
// (16 KB) to cut producer arch regs. lsum -> consumer VALU (idle slack) +
// epilogue shuffles; drops R18's ones-MFMA (k-coverage over (g,j) is a
// permutation -> per-lane partial + shfl_xor(16,32) is exact).
// Registers (union): o[8][4]=128 AGPR + ~80 arch ~ 210 < 256 @ 2 waves/SIMD.
// KV traffic: K,V each read ONCE per block (512 KB vs 1 MB before).
// Role = (wid ^ blockIdx)&1 so co-resident blocks stagger producer SIMDs.
// 34 uniform barriers (1 Q-stage + 32 phases + 1 tail/overlay... see below).
// XCD swizzle (R8) kept.

__global__ __launch_bounds__(256, 2) void attn_kernel(
    const float* __restrict__ Qf,
    const _Float16* __restrict__ Kf,
    const _Float16* __restrict__ Vf,
    float* __restrict__ out) {
    __shared__ __align__(16) char smem[49152];
    _Float16* pbp = (_Float16*)smem;                 // [ks][buf][nq8][lane][8h] = 32 KB
    _Float16* qls = (_Float16*)(smem + 32768);       // [nq8][kh2][lane][8h] = 16 KB
    float (*red)[64] = (float (*)[64])smem;          // epilogue overlay [136][64]

    const int tid = threadIdx.x;
    const int wid = tid >> 6;
    const int lane = tid & 63;
    const int ln15 = lane & 15;
    const int g = lane >> 4;

    const int bh = blockIdx.x & 31;          // head-major: head h -> XCD h%8
    const int qidx = blockIdx.x >> 5;        // 16 q-blocks per head (128 q each)
    const int ks = wid >> 1;                 // k-split half (16 tiles each)
    const int role = (wid ^ (int)blockIdx.x) & 1;  // 0=producer, 1=consumer
    const int q0 = qidx * 128;
    const int lo = lane * 8;                 // lane offset in halves (16 B)

    // ---- stage Q fragments into LDS (all 4 waves; wave w -> nq {2w, 2w+1}) ----
    {
        const float* Qg = Qf + (bh * S_LEN + q0) * DHEAD;
#pragma unroll
        for (int i = 0; i < 4; ++i) {
            int nq = wid * 2 + (i >> 1);
            int kh = i & 1;
            const float4* qs = (const float4*)(Qg + (nq * 16 + ln15) * DHEAD + kh * 32 + g * 8);
            float4 a = qs[0], b = qs[1];
            half8_t h = {(_Float16)a.x, (_Float16)a.y, (_Float16)a.z, (_Float16)a.w,
                         (_Float16)b.x, (_Float16)b.y, (_Float16)b.z, (_Float16)b.w};
            *(half8_t*)(qls + (nq * 2 + kh) * 512 + lo) = h;
        }
    }
    __syncthreads();

    const _Float16* kb = Kf + bh * (NTILES * TILE_HALVES) + ks * 16 * TILE_HALVES;
    const _Float16* vb = Vf + bh * (NTILES * TILE_HALVES) + ks * 16 * TILE_HALVES;

    float4_t o[8][4];
    float lsum[8];
#pragma unroll
    for (int nq = 0; nq < 8; ++nq) {
        lsum[nq] = 0.f;
#pragma unroll
        for (int vt = 0; vt < 4; ++vt) o[nq][vt] = (float4_t){0.f, 0.f, 0.f, 0.f};
    }

    // 32 chunk-phases: phase p: producer computes chunk p -> pb[p&1];
    // consumer consumes chunk p-1 from pb[(p-1)&1]. Barrier per phase.
#pragma unroll 2
    for (int p = 0; p < 32; ++p) {
        if (role == 0) {
            const int t = p >> 1, c = p & 1;
            const int base = t * TILE_HALVES;
            half8_t kA[4];
#pragma unroll
            for (int i = 0; i < 4; ++i)
                kA[i] = *(const half8_t*)(kb + base + (4 * c + i) * 512 + lo);
            _Float16* pbw = pbp + (ks * 2 + (p & 1)) * 4096 + lo;
#pragma unroll
            for (int nq = 0; nq < 8; ++nq) {
                half8_t q0f = *(const half8_t*)(qls + (nq * 2 + 0) * 512 + lo);
                half8_t q1f = *(const half8_t*)(qls + (nq * 2 + 1) * 512 + lo);
                float4_t a0 = (float4_t){0.f, 0.f, 0.f, 0.f};
                float4_t a1 = (float4_t){0.f, 0.f, 0.f, 0.f};
                a0 = __builtin_amdgcn_mfma_f32_16x16x32_f16(kA[0], q0f, a0, 0, 0, 0);
                a0 = __builtin_amdgcn_mfma_f32_16x16x32_f16(kA[1], q1f, a0, 0, 0, 0);
                a1 = __builtin_amdgcn_mfma_f32_16x16x32_f16(kA[2], q0f, a1, 0, 0, 0);
                a1 = __builtin_amdgcn_mfma_f32_16x16x32_f16(kA[3], q1f, a1, 0, 0, 0);
                float p0 = __builtin_amdgcn_exp2f(a0[0]);
                float p1 = __builtin_amdgcn_exp2f(a0[1]);
                float p2 = __builtin_amdgcn_exp2f(a0[2]);
                float p3 = __builtin_amdgcn_exp2f(a0[3]);
                float p4 = __builtin_amdgcn_exp2f(a1[0]);
                float p5 = __builtin_amdgcn_exp2f(a1[1]);
                float p6 = __builtin_amdgcn_exp2f(a1[2]);
                float p7 = __builtin_amdgcn_exp2f(a1[3]);
                half2_t e01 = __builtin_bit_cast(half2_t, __builtin_amdgcn_cvt_pkrtz(p0, p1));
                half2_t e23 = __builtin_bit_cast(half2_t, __builtin_amdgcn_cvt_pkrtz(p2, p3));
                half2_t e45 = __builtin_bit_cast(half2_t, __builtin_amdgcn_cvt_pkrtz(p4, p5));
                half2_t e67 = __builtin_bit_cast(half2_t, __builtin_amdgcn_cvt_pkrtz(p6, p7));
                half8_t pbreg = {e01[0], e01[1], e23[0], e23[1],
                                 e45[0], e45[1], e67[0], e67[1]};
                *(half8_t*)(pbw + nq * 512) = pbreg;
            }
        } else if (p > 0) {
            const int tc = p - 1;
            const int t = tc >> 1, c = tc & 1, rbuf = tc & 1;
            const int base = t * TILE_HALVES;
            half8_t vA[4];
#pragma unroll
            for (int vt = 0; vt < 4; ++vt)
                vA[vt] = *(const half8_t*)(vb + base + (vt * 2 + c) * 512 + lo);
            const _Float16* pbr0 = pbp + (ks * 2 + rbuf) * 4096 + lo;
#pragma unroll
            for (int nq = 0; nq < 8; ++nq) {
                half8_t pbr = *(const half8_t*)(pbr0 + nq * 512);
#pragma unroll
                for (int vt = 0; vt < 4; ++vt)
                    o[nq][vt] = __builtin_amdgcn_mfma_f32_16x16x32_f16(vA[vt], pbr, o[nq][vt], 0, 0, 0);
                lsum[nq] += ((float)pbr[0] + (float)pbr[1]) + ((float)pbr[2] + (float)pbr[3])
                          + ((float)pbr[4] + (float)pbr[5]) + ((float)pbr[6] + (float)pbr[7]);
            }
        }
        __syncthreads();
    }

    // ---- tail: consumer processes chunk 31 from pb buf 1 ----
    if (role == 1) {
        const int t = 15, c = 1, rbuf = 1;
        const int base = t * TILE_HALVES;
        half8_t vA[4];
#pragma unroll
        for (int vt = 0; vt < 4; ++vt)
            vA[vt] = *(const half8_t*)(vb + base + (vt * 2 + c) * 512 + lo);
        const _Float16* pbr0 = pbp + (ks * 2 + rbuf) * 4096 + lo;
#pragma unroll
        for (int nq = 0; nq < 8; ++nq) {
            half8_t pbr = *(const half8_t*)(pbr0 + nq * 512);
#pragma unroll
            for (int vt = 0; vt < 4; ++vt)
                o[nq][vt] = __builtin_amdgcn_mfma_f32_16x16x32_f16(vA[vt], pbr, o[nq][vt], 0, 0, 0);
            lsum[nq] += ((float)pbr[0] + (float)pbr[1]) + ((float)pbr[2] + (float)pbr[3])
                      + ((float)pbr[4] + (float)pbr[5]) + ((float)pbr[6] + (float)pbr[7]);
        }
        // cross-lane l reduction over k-groups (exact: (g,j) covers each k once)
#pragma unroll
        for (int nq = 0; nq < 8; ++nq) {
            float l = lsum[nq];
            l += __shfl_xor(l, 16, 64);
            l += __shfl_xor(l, 32, 64);
            lsum[nq] = l;
        }
    }
    __syncthreads();    // all pb reads done; overlay becomes safe

    // ---- split-K combine between the two consumers via LDS overlay ----
    if (role == 1 && ks == 1) {
#pragma unroll
        for (int nq = 0; nq < 8; ++nq) {
#pragma unroll
            for (int vt = 0; vt < 4; ++vt)
#pragma unroll
                for (int r = 0; r < 4; ++r)
                    red[nq * 16 + vt * 4 + r][lane] = o[nq][vt][r];
            red[128 + nq][lane] = lsum[nq];
        }
    }
    __syncthreads();
    if (role == 1 && ks == 0) {
#pragma unroll
        for (int nq = 0; nq < 8; ++nq) {
            float lt = lsum[nq] + red[128 + nq][lane];
            float inv_l = 1.0f / lt;
            int qrow = q0 + nq * 16 + ln15;
            float* og = out + (bh * S_LEN + qrow) * DHEAD;
#pragma unroll
            for (int vt = 0; vt < 4; ++vt) {
                float4_t vals;
#pragma unroll
                for (int r = 0; r < 4; ++r)
                    vals[r] = (o[nq][vt][r] + red[nq * 16 + vt * 4 + r][lane]) * inv_l;
                *(float4_t*)(og + vt * 16 + g * 4) = vals;
            }
        }
    }
}

// ---------------- launch ----------------

extern "C" void kernel_launch(void* const* d_in, const int* in_sizes, int n_in,
                              void* d_out, int out_size, void* d_ws, size_t ws_size,
                              hipStream_t stream) {
    const float* Kin = (const float*)d_in[0];
    const float* Qin = (const float*)d_in[1];
    const float* Vin = (const float*)d_in[2];
    float* out = (float*)d_out;

    _Float16* Kf = (_Float16*)d_ws;                 // 8 MB
    _Float16* Vf = Kf + TENS_ELEMS;                 // 8 MB

    prep_kernel<<<BHEADS * NTILES, 256, 0, stream>>>(Kin, Vin, Kf, Vf);
    attn_kernel<<<BHEADS * 16, 256, 0, stream>>>(Qin, Kf, Vf, out);
}

// Round 13
// 125.627 us; speedup vs baseline: 1.0545x; 1.0545x over previous
//
#include <hip/hip_runtime.h>

// B=2, H=16, S=2048, DK=DV=64; out flat = [B,H,S,DV] flat (raw reshape).
#define S_LEN 2048
#define DHEAD 64
#define BHEADS 32
#define NTILES 32                       // key tiles of 64
#define HEAD_ELEMS (S_LEN * DHEAD)
#define TENS_ELEMS (BHEADS * HEAD_ELEMS)
#define TILE_HALVES 4096                // 8 KB per (bh,tile) fragment block

typedef _Float16 half8_t __attribute__((ext_vector_type(8)));
typedef _Float16 half4_t __attribute__((ext_vector_type(4)));
typedef _Float16 half2_t __attribute__((ext_vector_type(2)));
typedef float float4_t __attribute__((ext_vector_type(4)));

// 1/sqrt(64) * log2(e), folded into K so scores land in exp2 domain
#define SC_LOG2E 0.18033688011112042f

// Fragment-linear layouts (16 B per lane per fragment):
//  Kf[bh][t][f=mt*2+kh][lane] : K[t*64 + mt*16 + (lane&15)][kh*32 + (lane>>4)*8 + j] * SC
//  Vf[bh][t][fv=vt*2+c][lane][j] : V[t*64 + c*32 + (j>>2)*16 + (lane>>4)*4 + (j&3)]
//                                   [vt*16 + (lane&15)]
// Key fact (R9): Vf's k-ordering equals the k-ordering of a P^T B-operand
// built by concatenating QK sub-tile outputs 2c (regs 0-3) and 2c+1 (regs
// 4-7), so PV can use mfma_f32_16x16x32_f16 directly — half the PV MFMAs.

// ---------------- prepass: build fragment-ordered K/VT ----------------
__global__ __launch_bounds__(256) void prep_kernel(const float* __restrict__ K,
                                                   const float* __restrict__ V,
                                                   _Float16* __restrict__ Kf,
                                                   _Float16* __restrict__ Vf) {
    __shared__ _Float16 tile[64][72];   // V tile [s][v], padded
    const int bh = blockIdx.x >> 5;
    const int t = blockIdx.x & 31;
    const int tid = threadIdx.x;

    const float* Ksrc = K + (bh * S_LEN + t * 64) * DHEAD;
    const float4* vs = (const float4*)(V + (bh * S_LEN + t * 64) * DHEAD);
#pragma unroll
    for (int it = 0; it < 4; ++it) {
        int i = it * 256 + tid;                 // 1024 float4 = 64x64 floats
        float4 vv = vs[i];
        int r = i >> 4, c4 = (i & 15) * 4;
        half4_t hv = {(_Float16)vv.x, (_Float16)vv.y, (_Float16)vv.z, (_Float16)vv.w};
        *(half4_t*)&tile[r][c4] = hv;
    }

    // K fragments: pure permutation of the fp32 tile, no LDS needed
    _Float16* kd = Kf + (bh * NTILES + t) * TILE_HALVES;
#pragma unroll
    for (int it = 0; it < 2; ++it) {
        int c = it * 256 + tid;                 // 512 chunks of 16 B
        int f = c >> 6, lane = c & 63;
        int row = (f >> 1) * 16 + (lane & 15);
        int d0 = (f & 1) * 32 + (lane >> 4) * 8;
        const float4* s = (const float4*)(Ksrc + row * DHEAD + d0);
        float4 a = s[0], b = s[1];
        half8_t h = {(_Float16)(a.x * SC_LOG2E), (_Float16)(a.y * SC_LOG2E),
                     (_Float16)(a.z * SC_LOG2E), (_Float16)(a.w * SC_LOG2E),
                     (_Float16)(b.x * SC_LOG2E), (_Float16)(b.y * SC_LOG2E),
                     (_Float16)(b.z * SC_LOG2E), (_Float16)(b.w * SC_LOG2E)};
        *(half8_t*)(kd + c * 8) = h;
    }
    __syncthreads();

    // VT fragments: transpose gather from LDS
    _Float16* vd = Vf + (bh * NTILES + t) * TILE_HALVES;
#pragma unroll
    for (int it = 0; it < 2; ++it) {
        int c = it * 256 + tid;
        int fv = c >> 6, lane = c & 63;
        int vt = fv >> 1, ktp = fv & 1;
        int v = vt * 16 + (lane & 15);
        int g = lane >> 4;
        half8_t h;
#pragma unroll
        for (int j = 0; j < 8; ++j) {
            int key = ktp * 32 + (j >> 2) * 16 + g * 4 + (j & 3);
            h[j] = tile[key][v];
        }
        *(half8_t*)(vd + c * 8) = h;
    }
}

// -------- attention: R0 structure + lsum via ones-MFMA (FINAL, R18) --------
// Block = 4 waves = 2 q-groups (64 queries each) x 2 k-splits (16 tiles each).
// Complete session ledger (MI355X, all measured):
//  R10/R12: reg cap below ~192-240 unified footprint => spill catastrophe
//           (o[4][4]=64 AGPR counts against the unified file!).
//  R11: manual register prefetch = neutral (compiler already pipelines).
//  R13: 4 waves/SIMD + 2x traffic = null. R14: LDS-staged KV = null.
//  R15: setprio = -9%. R16: LDS + 4 waves + nq=2 = -10% (util flat at 28/34
//       even at occupancy 31%). R17: chunk-interleaved ILP schedule = null.
//  R19: 3 waves/SIMD with full nq=4 ILP = null (occupancy closed for good).
//  R20: producer/consumer wave specialization = -26% (barrier-serialized to
//       the producer's critical path; handoff overhead > overlap gained).
//  R18 (THIS KERNEL): lsum row-sum moved to the MFMA pipe = WIN 45.0->43.3,
//       counter deltas matched prediction (VALU 34->30, Mfma 30->34).
// Conclusion: wall = serialized pipe issue time + dependency drain in the
// compiler's already-optimal barrier-free schedule. Every coverage lever
// (occupancy/traffic/source/schedule/priority/specialization) measured null
// or negative; only WORK DELETION moved the wall (~1:1). Residual ~36%
// both-pipes-idle is not reachable from plain-HIP source on this structure.
// XCD swizzle (R8) kept. nq=4 + K=32 PV (R9) kept. ones-MFMA lsum (R18) kept.

__global__ __launch_bounds__(256, 2) void attn_kernel(
    const float* __restrict__ Qf,
    const _Float16* __restrict__ Kf,
    const _Float16* __restrict__ Vf,
    float* __restrict__ out) {
    __shared__ float red[2][68][64];    // [qg][64 o-floats + 4 lsum][lane]

    const int tid = threadIdx.x;
    const int wid = tid >> 6;
    const int lane = tid & 63;
    const int ln15 = lane & 15;
    const int g = lane >> 4;

    const int bh = blockIdx.x & 31;          // head-major: head h -> XCD h%8
    const int qidx = blockIdx.x >> 5;        // 16 q-blocks per head (128 q each)
    const int qg = wid >> 1;                 // q-group within block
    const int ks = wid & 1;                  // k-split half
    const int q0 = qidx * 128 + qg * 64;
    const int t0 = ks * 16;                  // this wave's 16 key tiles

    // ---- Q fragments (B-operand of 16x16x32), direct global fp32 -> f16 ----
    const float* Qg = Qf + (bh * S_LEN + q0) * DHEAD;
    half8_t qf[4][2];
#pragma unroll
    for (int nq = 0; nq < 4; ++nq)
#pragma unroll
        for (int kh = 0; kh < 2; ++kh) {
            const float4* qs = (const float4*)(Qg + (nq * 16 + ln15) * DHEAD + kh * 32 + g * 8);
            float4 a = qs[0], b = qs[1];
            qf[nq][kh] = (half8_t){(_Float16)a.x, (_Float16)a.y, (_Float16)a.z, (_Float16)a.w,
                                   (_Float16)b.x, (_Float16)b.y, (_Float16)b.z, (_Float16)b.w};
        }

    const _Float16* kb = Kf + bh * (NTILES * TILE_HALVES) + t0 * TILE_HALVES;
    const _Float16* vb = Vf + bh * (NTILES * TILE_HALVES) + t0 * TILE_HALVES;
    const int lo = lane * 8;                  // lane offset in halves

    const half8_t vones = {(_Float16)1.f, (_Float16)1.f, (_Float16)1.f, (_Float16)1.f,
                           (_Float16)1.f, (_Float16)1.f, (_Float16)1.f, (_Float16)1.f};

    float4_t o[4][4];
    float4_t o4[4];                     // row-sum accumulators (ones-MFMA)
#pragma unroll
    for (int nq = 0; nq < 4; ++nq) {
#pragma unroll
        for (int vt = 0; vt < 4; ++vt) o[nq][vt] = (float4_t){0.f, 0.f, 0.f, 0.f};
        o4[nq] = (float4_t){0.f, 0.f, 0.f, 0.f};
    }

#pragma unroll 2
    for (int t = 0; t < 16; ++t) {
        const int base = t * TILE_HALVES;
        half8_t kf[8], vf[8];
#pragma unroll
        for (int f = 0; f < 8; ++f) kf[f] = *(const half8_t*)(kb + base + f * 512 + lo);
#pragma unroll
        for (int f = 0; f < 8; ++f) vf[f] = *(const half8_t*)(vb + base + f * 512 + lo);

        // two 32-key chunks; QK -> exp2 -> PV (K=32) per chunk
#pragma unroll
        for (int c = 0; c < 2; ++c) {
            half8_t pb[4];
#pragma unroll
            for (int h = 0; h < 2; ++h) {
                const int mt = 2 * c + h;
                half8_t a0 = kf[mt * 2];
                half8_t a1 = kf[mt * 2 + 1];
#pragma unroll
                for (int nq = 0; nq < 4; ++nq) {
                    float4_t c0 = (float4_t){0.f, 0.f, 0.f, 0.f};
                    c0 = __builtin_amdgcn_mfma_f32_16x16x32_f16(a0, qf[nq][0], c0, 0, 0, 0);
                    c0 = __builtin_amdgcn_mfma_f32_16x16x32_f16(a1, qf[nq][1], c0, 0, 0, 0);
                    float p0 = __builtin_amdgcn_exp2f(c0[0]);
                    float p1 = __builtin_amdgcn_exp2f(c0[1]);
                    float p2 = __builtin_amdgcn_exp2f(c0[2]);
                    float p3 = __builtin_amdgcn_exp2f(c0[3]);
                    half2_t plo = __builtin_bit_cast(half2_t, __builtin_amdgcn_cvt_pkrtz(p0, p1));
                    half2_t phi = __builtin_bit_cast(half2_t, __builtin_amdgcn_cvt_pkrtz(p2, p3));
                    pb[nq][h * 4 + 0] = plo[0];
                    pb[nq][h * 4 + 1] = plo[1];
                    pb[nq][h * 4 + 2] = phi[0];
                    pb[nq][h * 4 + 3] = phi[1];
                }
            }
            // ---- O^T += V^T . P^T over this 32-key chunk (K=32 MFMA) ----
#pragma unroll
            for (int vt = 0; vt < 4; ++vt) {
                half8_t va = vf[vt * 2 + c];
#pragma unroll
                for (int nq = 0; nq < 4; ++nq)
                    o[nq][vt] = __builtin_amdgcn_mfma_f32_16x16x32_f16(va, pb[nq], o[nq][vt], 0, 0, 0);
            }
            // ---- lsum via ones-MFMA: o4[nq][*] += sum_k P^T[k][q] ----
#pragma unroll
            for (int nq = 0; nq < 4; ++nq)
                o4[nq] = __builtin_amdgcn_mfma_f32_16x16x32_f16(vones, pb[nq], o4[nq], 0, 0, 0);
        }
    }

    // lsum[nq] = o4[nq][0]: D[v][q] is v-independent => replicated over regs
    // AND g-groups already (no cross-lane reduction needed).
    float lsum[4];
#pragma unroll
    for (int nq = 0; nq < 4; ++nq) lsum[nq] = o4[nq][0];

    // ---- split-K combine via LDS (conflict-free column layout) ----
    if (ks == 1) {
#pragma unroll
        for (int nq = 0; nq < 4; ++nq)
#pragma unroll
            for (int vt = 0; vt < 4; ++vt)
#pragma unroll
                for (int r = 0; r < 4; ++r)
                    red[qg][nq * 16 + vt * 4 + r][lane] = o[nq][vt][r];
#pragma unroll
        for (int nq = 0; nq < 4; ++nq) red[qg][64 + nq][lane] = lsum[nq];
    }
    __syncthreads();
    if (ks == 0) {
#pragma unroll
        for (int nq = 0; nq < 4; ++nq) {
            float lt = lsum[nq] + red[qg][64 + nq][lane];
            float inv_l = 1.0f / lt;
            int qg_global = q0 + nq * 16 + ln15;
            float* og = out + (bh * S_LEN + qg_global) * DHEAD;
#pragma unroll
            for (int vt = 0; vt < 4; ++vt) {
                float4_t vals;
#pragma unroll
                for (int r = 0; r < 4; ++r)
                    vals[r] = (o[nq][vt][r] + red[qg][nq * 16 + vt * 4 + r][lane]) * inv_l;
                *(float4_t*)(og + vt * 16 + g * 4) = vals;
            }
        }
    }
}

// ---------------- launch ----------------

extern "C" void kernel_launch(void* const* d_in, const int* in_sizes, int n_in,
                              void* d_out, int out_size, void* d_ws, size_t ws_size,
                              hipStream_t stream) {
    const float* Kin = (const float*)d_in[0];
    const float* Qin = (const float*)d_in[1];
    const float* Vin = (const float*)d_in[2];
    float* out = (float*)d_out;

    _Float16* Kf = (_Float16*)d_ws;                 // 8 MB
    _Float16* Vf = Kf + TENS_ELEMS;                 // 8 MB

    prep_kernel<<<BHEADS * NTILES, 256, 0, stream>>>(Kin, Vin, Kf, Vf);
    attn_kernel<<<BHEADS * 16, 256, 0, stream>>>(Qin, Kf, Vf, out);
}